// Round 3
// baseline (732.501 us; speedup 1.0000x reference)
//
#include <hip/hip_runtime.h>

#define N_SRC   100000
#define N_TGT   50000
#define N_EDGES 1000000
#define NEG     0.2

// ===========================================================================
// CSR/CSC build + gather. All edge-score math in f64 so summation order
// cannot move the result (denominators nearly cancel for some rows).
// ===========================================================================

// ---------------------------------------------------------------------------
// GEMM: msg = x @ w (K=128, N=64). One LANE per row; acc[64] in VGPRs.
// evec[row] = msg[row] . att[att_off:+64], accumulated in f64, stored f64.
// ---------------------------------------------------------------------------
__global__ __launch_bounds__(256) void gemm_rowlane(
    const float* __restrict__ x, const float* __restrict__ w,
    const float* __restrict__ att, int att_off, int nrows,
    float* __restrict__ msg, double* __restrict__ evec)
{
    const int row = blockIdx.x * blockDim.x + threadIdx.x;
    if (row >= nrows) return;
    const float* xr = x + (size_t)row * 128;

    float acc[64];
    #pragma unroll
    for (int c = 0; c < 64; ++c) acc[c] = 0.f;

    for (int kc = 0; kc < 128; kc += 16) {
        float4 xv[4];
        #pragma unroll
        for (int q = 0; q < 4; ++q)
            xv[q] = *(const float4*)(xr + kc + 4 * q);
        #pragma unroll
        for (int kk = 0; kk < 16; ++kk) {
            const float xk = ((const float*)xv)[kk];
            const float* wr = w + (size_t)(kc + kk) * 64;   // wave-uniform addr
            #pragma unroll
            for (int c = 0; c < 64; ++c)
                acc[c] = fmaf(xk, wr[c], acc[c]);
        }
    }

    double e = 0.0;
    #pragma unroll
    for (int c = 0; c < 64; ++c) e += (double)acc[c] * (double)att[att_off + c];

    float* mo = msg + (size_t)row * 64;
    #pragma unroll
    for (int q = 0; q < 16; ++q)
        *(float4*)(mo + 4 * q) = *(float4*)(acc + 4 * q);
    evec[row] = e;
}

// ---------------------------------------------------------------------------
__global__ __launch_bounds__(256) void hist_kernel(
    const int* __restrict__ rows, const int* __restrict__ cols,
    int* __restrict__ cnt_r, int* __restrict__ cnt_c)
{
    const int i = blockIdx.x * blockDim.x + threadIdx.x;
    if (i >= N_EDGES) return;
    atomicAdd(&cnt_r[rows[i]], 1);
    atomicAdd(&cnt_c[cols[i]], 1);
}

// ---------------------------------------------------------------------------
// Exclusive scan. block 0 -> rows (N_TGT), block 1 -> cols (N_SRC).
// ---------------------------------------------------------------------------
__global__ __launch_bounds__(1024) void scan_two(
    const int* __restrict__ cnt_r, const int* __restrict__ cnt_c,
    int* __restrict__ ptr_r, int* __restrict__ ofs_r,
    int* __restrict__ ptr_c, int* __restrict__ ofs_c)
{
    const int n    = blockIdx.x ? N_SRC : N_TGT;
    const int* cnt = blockIdx.x ? cnt_c : cnt_r;
    int* ptr       = blockIdx.x ? ptr_c : ptr_r;
    int* ofs       = blockIdx.x ? ofs_c : ofs_r;
    const int tid  = threadIdx.x;
    const int lane = tid & 63, wid = tid >> 6;
    __shared__ int wsum[16];

    const int chunk = (n + 1023) / 1024;
    const int lo = min(tid * chunk, n);
    const int hi = min(lo + chunk, n);

    int s = 0;
    for (int j = lo; j < hi; ++j) s += cnt[j];

    int v = s;
    #pragma unroll
    for (int d = 1; d < 64; d <<= 1) {
        int t = __shfl_up(v, d);
        if (lane >= d) v += t;
    }
    if (lane == 63) wsum[wid] = v;
    __syncthreads();
    if (tid == 0) {
        int a = 0;
        #pragma unroll
        for (int w2 = 0; w2 < 16; ++w2) { int t = wsum[w2]; wsum[w2] = a; a += t; }
    }
    __syncthreads();

    int run = v - s + wsum[wid];
    for (int j = lo; j < hi; ++j) { ptr[j] = run; ofs[j] = run; run += cnt[j]; }
    if (tid == 1023) ptr[n] = run;
}

// ---------------------------------------------------------------------------
// Scatter edges into both sorted lists. Payload = (other_idx, nbhd) : 8 B.
// ---------------------------------------------------------------------------
__global__ __launch_bounds__(256) void scatter_kernel(
    const int* __restrict__ rows, const int* __restrict__ cols,
    const float* __restrict__ nbhd,
    int* __restrict__ ofs_r, int* __restrict__ ofs_c,
    int2* __restrict__ srtT, int2* __restrict__ srtS)
{
    const int i = blockIdx.x * blockDim.x + threadIdx.x;
    if (i >= N_EDGES) return;
    const int r = rows[i], c = cols[i];
    const int nb = __float_as_int(nbhd[i]);
    const int p = atomicAdd(&ofs_r[r], 1);
    srtT[p] = make_int2(c, nb);
    const int q = atomicAdd(&ofs_c[c], 1);
    srtS[q] = make_int2(r, nb);
}

// ---------------------------------------------------------------------------
// Gather: one wave per output row, lane = feature. Edge score v recomputed
// in f64 from es/et (f64); den and acc accumulated in f64.
// ---------------------------------------------------------------------------
__global__ __launch_bounds__(256) void gather_both(
    const int2* __restrict__ srtT, const int* __restrict__ ptr_r,
    const float* __restrict__ s_msg, float* __restrict__ msg_tgt,
    const int2* __restrict__ srtS, const int* __restrict__ ptr_c,
    const float* __restrict__ t_msg, float* __restrict__ msg_src,
    const double* __restrict__ es_d, const double* __restrict__ et_d)
{
    const int gw   = (blockIdx.x * blockDim.x + threadIdx.x) >> 6;
    const int lane = threadIdx.x & 63;

    const int2* srt; const int* ptr; const float* min_; float* out;
    const double* other_d; double base; int row;
    if (gw < N_TGT) {
        srt = srtT; ptr = ptr_r; min_ = s_msg; out = msg_tgt;
        other_d = es_d; row = gw; base = et_d[row];
    } else {
        row = gw - N_TGT;
        if (row >= N_SRC) return;
        srt = srtS; ptr = ptr_c; min_ = t_msg; out = msg_src;
        other_d = et_d; base = es_d[row];
    }

    const int b = ptr[row], e = ptr[row + 1];
    double den = 0.0, acc = 0.0;

    for (int j0 = b; j0 < e; j0 += 64) {
        const int m = e - j0;
        int oidx = 0; float nb = 0.f; double v = 0.0;
        if (lane < m) {
            const int2 pay = srt[j0 + lane];
            oidx = pay.x;
            nb   = __int_as_float(pay.y);
            const double sv = base + other_d[oidx];
            v = (sv >= 0.0) ? sv : NEG * sv;
        }
        den += v;
        const float wf = (float)(v * (double)nb);

        const int cnt = m < 64 ? m : 64;
        for (int j = 0; j < cnt; ++j) {
            const int   c = __shfl(oidx, j);
            const float w = __shfl(wf, j);
            acc += (double)w * (double)min_[(size_t)c * 64 + lane];
        }
    }
    #pragma unroll
    for (int s = 32; s; s >>= 1) den += __shfl_xor(den, s);
    const double inv = (den != 0.0) ? 1.0 / den : 0.0;
    out[(size_t)row * 64 + lane] = (float)(acc * inv);
}

// ===========================================================================
// FALLBACK PATH (round-0, passed at 675 us) — only if ws is too small
// ===========================================================================
__global__ __launch_bounds__(256) void gemm_msg(
    const float* __restrict__ x, const float* __restrict__ w,
    const float* __restrict__ att, int att_off,
    float* __restrict__ msg, float* __restrict__ evec)
{
    __shared__ float wls[128 * 64];
    __shared__ float xs[4 * 128];
    const int tid = threadIdx.x;
    #pragma unroll
    for (int i = 0; i < 8; ++i)
        ((float4*)wls)[tid + i * 256] = ((const float4*)w)[tid + i * 256];
    const int row0 = blockIdx.x * 4;
    if (tid < 128)
        ((float4*)xs)[tid] = ((const float4*)(x + (size_t)row0 * 128))[tid];
    __syncthreads();
    const int r = tid >> 6, c = tid & 63;
    float acc = 0.f;
    #pragma unroll
    for (int k = 0; k < 128; ++k)
        acc += xs[r * 128 + k] * wls[k * 64 + c];
    const int grow = row0 + r;
    msg[(size_t)grow * 64 + c] = acc;
    float v = acc * att[att_off + c];
    #pragma unroll
    for (int s = 32; s > 0; s >>= 1) v += __shfl_xor(v, s);
    if (c == 0) evec[grow] = v;
}

__global__ __launch_bounds__(256) void edge_pass1(
    const int* __restrict__ rows, const int* __restrict__ cols,
    const float* __restrict__ es, const float* __restrict__ et,
    float* __restrict__ e_den, float* __restrict__ f_den)
{
    const int i = blockIdx.x * blockDim.x + threadIdx.x;
    if (i >= N_EDGES) return;
    const int r = rows[i], c = cols[i];
    const float s = es[c] + et[r];
    const float v = (s >= 0.f) ? s : 0.2f * s;
    atomicAdd(&e_den[r], v);
    atomicAdd(&f_den[c], v);
}

__global__ __launch_bounds__(256) void edge_pass2(
    const int* __restrict__ rows, const int* __restrict__ cols,
    const float* __restrict__ es, const float* __restrict__ et,
    const float* __restrict__ e_den, const float* __restrict__ f_den,
    const float* __restrict__ nbhd,
    const float* __restrict__ s_msg, const float* __restrict__ t_msg,
    float* __restrict__ msg_src, float* __restrict__ msg_tgt)
{
    const int wid    = (blockIdx.x * blockDim.x + threadIdx.x) >> 6;
    const int lane   = threadIdx.x & 63;
    const int nwaves = (gridDim.x * blockDim.x) >> 6;
    for (int i = wid; i < N_EDGES; i += nwaves) {
        const int r = rows[i], c = cols[i];
        const float s  = es[c] + et[r];
        const float ev = (s >= 0.f) ? s : 0.2f * s;
        const float nb = nbhd[i];
        const float wst = ev / e_den[r] * nb;
        const float wts = ev / f_den[c] * nb;
        atomicAdd(&msg_tgt[(size_t)r * 64 + lane], wst * s_msg[(size_t)c * 64 + lane]);
        atomicAdd(&msg_src[(size_t)c * 64 + lane], wts * t_msg[(size_t)r * 64 + lane]);
    }
}

// ===========================================================================
extern "C" void kernel_launch(void* const* d_in, const int* in_sizes, int n_in,
                              void* d_out, int out_size, void* d_ws, size_t ws_size,
                              hipStream_t stream)
{
    const float* x_source = (const float*)d_in[0];
    const float* x_target = (const float*)d_in[1];
    const float* w_s      = (const float*)d_in[2];
    const float* w_t      = (const float*)d_in[3];
    const float* att      = (const float*)d_in[4];
    const float* nbhd     = (const float*)d_in[5];
    const int*   rows     = (const int*)d_in[6];
    const int*   cols     = (const int*)d_in[7];

    float* out     = (float*)d_out;
    float* msg_src = out;                       // (N_SRC, 64)
    float* msg_tgt = out + (size_t)N_SRC * 64;  // (N_TGT, 64)

    char* ws = (char*)d_ws;
    // byte layout: total 57,400,016 B
    float*  s_msg = (float*) (ws + 0);           // 25,600,000
    float*  t_msg = (float*) (ws + 25600000);    // 12,800,000
    double* es_d  = (double*)(ws + 38400000);    //    800,000
    double* et_d  = (double*)(ws + 39200000);    //    400,000
    int*    cnt_r = (int*)   (ws + 39600000);    //    200,000
    int*    cnt_c = (int*)   (ws + 39800000);    //    400,000
    int*    ptr_r = (int*)   (ws + 40200000);    //    200,004
    int*    ptr_c = (int*)   (ws + 40400004);    //    400,004
    int*    ofs_r = (int*)   (ws + 40800008);    //    200,000
    int*    ofs_c = (int*)   (ws + 41000008);    //    400,000 (+8 pad)
    int2*   srtT  = (int2*)  (ws + 41400016);    //  8,000,000
    int2*   srtS  = (int2*)  (ws + 49400016);    //  8,000,000
    const size_t NEED = 57400016;

    if (ws_size >= NEED) {
        hipMemsetAsync(ws + 39600000, 0, 600000, stream);  // cnt_r + cnt_c

        gemm_rowlane<<<(N_SRC + 255) / 256, 256, 0, stream>>>(
            x_source, w_s, att, 0, N_SRC, s_msg, es_d);
        gemm_rowlane<<<(N_TGT + 255) / 256, 256, 0, stream>>>(
            x_target, w_t, att, 64, N_TGT, t_msg, et_d);

        hist_kernel<<<(N_EDGES + 255) / 256, 256, 0, stream>>>(rows, cols, cnt_r, cnt_c);
        scan_two<<<2, 1024, 0, stream>>>(cnt_r, cnt_c, ptr_r, ofs_r, ptr_c, ofs_c);
        scatter_kernel<<<(N_EDGES + 255) / 256, 256, 0, stream>>>(
            rows, cols, nbhd, ofs_r, ofs_c, srtT, srtS);

        gather_both<<<(N_TGT + N_SRC + 3) / 4, 256, 0, stream>>>(
            srtT, ptr_r, s_msg, msg_tgt, srtS, ptr_c, t_msg, msg_src, es_d, et_d);
    } else {
        // -------- fallback: round-0 atomic path --------
        float* f_es    = (float*)(ws + 38400000);
        float* f_et    = (float*)(ws + 38800000);
        float* f_e_den = (float*)(ws + 39000000);
        float* f_f_den = (float*)(ws + 39200000);

        hipMemsetAsync(out, 0, (size_t)out_size * sizeof(float), stream);
        hipMemsetAsync(ws + 39000000, 0, 600000, stream);

        gemm_msg<<<N_SRC / 4, 256, 0, stream>>>(x_source, w_s, att, 0,  s_msg, f_es);
        gemm_msg<<<N_TGT / 4, 256, 0, stream>>>(x_target, w_t, att, 64, t_msg, f_et);
        edge_pass1<<<(N_EDGES + 255) / 256, 256, 0, stream>>>(
            rows, cols, f_es, f_et, f_e_den, f_f_den);
        edge_pass2<<<2048, 256, 0, stream>>>(rows, cols, f_es, f_et, f_e_den, f_f_den,
                                             nbhd, s_msg, t_msg, msg_src, msg_tgt);
    }
}

// Round 4
// 608.192 us; speedup vs baseline: 1.2044x; 1.2044x over previous
//
#include <hip/hip_runtime.h>

#define N_SRC   100000
#define N_TGT   50000
#define N_EDGES 1000000
#define NEG     0.2

// ===========================================================================
// CSR/CSC build + gather. All edge-score math in f64 so summation order
// cannot move the result (denominators nearly cancel for some rows).
// ===========================================================================

// ---------------------------------------------------------------------------
// GEMM: msg = x @ w (K=128, N=64). block = 256 threads = 4 rows x 64 cols.
// w (128x64 = 32 KB) staged in LDS; all global traffic coalesced.
// evec[row] = msg[row] . att[att_off:+64] accumulated/stored in f64.
// ---------------------------------------------------------------------------
__global__ __launch_bounds__(256) void gemm_msg(
    const float* __restrict__ x, const float* __restrict__ w,
    const float* __restrict__ att, int att_off,
    float* __restrict__ msg, double* __restrict__ evec)
{
    __shared__ float wls[128 * 64];
    __shared__ float xs[4 * 128];
    const int tid = threadIdx.x;

    #pragma unroll
    for (int i = 0; i < 8; ++i)
        ((float4*)wls)[tid + i * 256] = ((const float4*)w)[tid + i * 256];

    const int row0 = blockIdx.x * 4;
    if (tid < 128)
        ((float4*)xs)[tid] = ((const float4*)(x + (size_t)row0 * 128))[tid];
    __syncthreads();

    const int r = tid >> 6;    // 0..3
    const int c = tid & 63;    // 0..63 (= lane)
    float acc = 0.f;
    #pragma unroll
    for (int k = 0; k < 128; ++k)
        acc = fmaf(xs[r * 128 + k], wls[k * 64 + c], acc);

    const int grow = row0 + r;
    msg[(size_t)grow * 64 + c] = acc;

    double v = (double)acc * (double)att[att_off + c];
    #pragma unroll
    for (int s = 32; s > 0; s >>= 1)
        v += __shfl_xor(v, s);
    if (c == 0) evec[grow] = v;
}

// ---------------------------------------------------------------------------
__global__ __launch_bounds__(256) void hist_kernel(
    const int* __restrict__ rows, const int* __restrict__ cols,
    int* __restrict__ cnt_r, int* __restrict__ cnt_c)
{
    const int i = blockIdx.x * blockDim.x + threadIdx.x;
    if (i >= N_EDGES) return;
    atomicAdd(&cnt_r[rows[i]], 1);
    atomicAdd(&cnt_c[cols[i]], 1);
}

// ---------------------------------------------------------------------------
// Exclusive scan, tiled + coalesced. block 0 -> rows (N_TGT), 1 -> cols (N_SRC).
// Per 4096-elem tile: int4/thread coalesced load, wave shfl-scan, 16-wave LDS
// scan, carry across tiles. ~38 tiles total.
// ---------------------------------------------------------------------------
__global__ __launch_bounds__(1024) void scan_two(
    const int* __restrict__ cnt_r, const int* __restrict__ cnt_c,
    int* __restrict__ ptr_r, int* __restrict__ ofs_r,
    int* __restrict__ ptr_c, int* __restrict__ ofs_c)
{
    const int n    = blockIdx.x ? N_SRC : N_TGT;
    const int* cnt = blockIdx.x ? cnt_c : cnt_r;
    int* ptr       = blockIdx.x ? ptr_c : ptr_r;
    int* ofs       = blockIdx.x ? ofs_c : ofs_r;
    const int tid  = threadIdx.x;
    const int lane = tid & 63, wid = tid >> 6;

    __shared__ int wsum[16];
    __shared__ int s_carry;
    if (tid == 0) s_carry = 0;
    __syncthreads();

    for (int base = 0; base < n; base += 4096) {
        const int idx = base + tid * 4;
        int4 v = make_int4(0, 0, 0, 0);
        if (idx + 3 < n) {
            v = *(const int4*)(cnt + idx);
        } else if (idx < n) {
            v.x = cnt[idx];
            if (idx + 1 < n) v.y = cnt[idx + 1];
            if (idx + 2 < n) v.z = cnt[idx + 2];
        }
        const int s = v.x + v.y + v.z + v.w;

        int p = s;                               // inclusive wave scan
        #pragma unroll
        for (int d = 1; d < 64; d <<= 1) {
            int t = __shfl_up(p, d);
            if (lane >= d) p += t;
        }
        if (lane == 63) wsum[wid] = p;
        __syncthreads();
        if (tid == 0) {
            int a = 0;
            #pragma unroll
            for (int i = 0; i < 16; ++i) { int t = wsum[i]; wsum[i] = a; a += t; }
        }
        __syncthreads();

        int run = s_carry + wsum[wid] + (p - s); // exclusive prefix, this thread
        if (idx     < n) { ptr[idx]     = run; ofs[idx]     = run; } run += v.x;
        if (idx + 1 < n) { ptr[idx + 1] = run; ofs[idx + 1] = run; } run += v.y;
        if (idx + 2 < n) { ptr[idx + 2] = run; ofs[idx + 2] = run; } run += v.z;
        if (idx + 3 < n) { ptr[idx + 3] = run; ofs[idx + 3] = run; } run += v.w;

        __syncthreads();                         // all done reading s_carry/wsum
        if (tid == 1023) s_carry = run;          // carry + tile total
        __syncthreads();
    }
    if (tid == 0) ptr[n] = s_carry;
}

// ---------------------------------------------------------------------------
// Scatter edges into both sorted lists. Payload = (other_idx, nbhd) : 8 B.
// ---------------------------------------------------------------------------
__global__ __launch_bounds__(256) void scatter_kernel(
    const int* __restrict__ rows, const int* __restrict__ cols,
    const float* __restrict__ nbhd,
    int* __restrict__ ofs_r, int* __restrict__ ofs_c,
    int2* __restrict__ srtT, int2* __restrict__ srtS)
{
    const int i = blockIdx.x * blockDim.x + threadIdx.x;
    if (i >= N_EDGES) return;
    const int r = rows[i], c = cols[i];
    const int nb = __float_as_int(nbhd[i]);
    const int p = atomicAdd(&ofs_r[r], 1);
    srtT[p] = make_int2(c, nb);
    const int q = atomicAdd(&ofs_c[c], 1);
    srtS[q] = make_int2(r, nb);
}

// ---------------------------------------------------------------------------
// Gather: one wave per output row, lane = feature. Edge score v recomputed
// in f64 from es/et (f64); den and acc accumulated in f64.
// ---------------------------------------------------------------------------
__global__ __launch_bounds__(256) void gather_both(
    const int2* __restrict__ srtT, const int* __restrict__ ptr_r,
    const float* __restrict__ s_msg, float* __restrict__ msg_tgt,
    const int2* __restrict__ srtS, const int* __restrict__ ptr_c,
    const float* __restrict__ t_msg, float* __restrict__ msg_src,
    const double* __restrict__ es_d, const double* __restrict__ et_d)
{
    const int gw   = (blockIdx.x * blockDim.x + threadIdx.x) >> 6;
    const int lane = threadIdx.x & 63;

    const int2* srt; const int* ptr; const float* min_; float* out;
    const double* other_d; double base; int row;
    if (gw < N_TGT) {
        srt = srtT; ptr = ptr_r; min_ = s_msg; out = msg_tgt;
        other_d = es_d; row = gw; base = et_d[row];
    } else {
        row = gw - N_TGT;
        if (row >= N_SRC) return;
        srt = srtS; ptr = ptr_c; min_ = t_msg; out = msg_src;
        other_d = et_d; base = es_d[row];
    }

    const int b = ptr[row], e = ptr[row + 1];
    double den = 0.0, acc = 0.0;

    for (int j0 = b; j0 < e; j0 += 64) {
        const int m = e - j0;
        int oidx = 0; float nb = 0.f; double v = 0.0;
        if (lane < m) {
            const int2 pay = srt[j0 + lane];
            oidx = pay.x;
            nb   = __int_as_float(pay.y);
            const double sv = base + other_d[oidx];
            v = (sv >= 0.0) ? sv : NEG * sv;
        }
        den += v;
        const float wf = (float)(v * (double)nb);

        const int cnt = m < 64 ? m : 64;
        for (int j = 0; j < cnt; ++j) {
            const int   c = __shfl(oidx, j);
            const float w = __shfl(wf, j);
            acc += (double)w * (double)min_[(size_t)c * 64 + lane];
        }
    }
    #pragma unroll
    for (int s = 32; s; s >>= 1) den += __shfl_xor(den, s);
    const double inv = (den != 0.0) ? 1.0 / den : 0.0;
    out[(size_t)row * 64 + lane] = (float)(acc * inv);
}

// ===========================================================================
extern "C" void kernel_launch(void* const* d_in, const int* in_sizes, int n_in,
                              void* d_out, int out_size, void* d_ws, size_t ws_size,
                              hipStream_t stream)
{
    const float* x_source = (const float*)d_in[0];
    const float* x_target = (const float*)d_in[1];
    const float* w_s      = (const float*)d_in[2];
    const float* w_t      = (const float*)d_in[3];
    const float* att      = (const float*)d_in[4];
    const float* nbhd     = (const float*)d_in[5];
    const int*   rows     = (const int*)d_in[6];
    const int*   cols     = (const int*)d_in[7];

    float* out     = (float*)d_out;
    float* msg_src = out;                       // (N_SRC, 64)
    float* msg_tgt = out + (size_t)N_SRC * 64;  // (N_TGT, 64)

    char* ws = (char*)d_ws;
    // byte layout: total 57,400,016 B
    float*  s_msg = (float*) (ws + 0);           // 25,600,000
    float*  t_msg = (float*) (ws + 25600000);    // 12,800,000
    double* es_d  = (double*)(ws + 38400000);    //    800,000
    double* et_d  = (double*)(ws + 39200000);    //    400,000
    int*    cnt_r = (int*)   (ws + 39600000);    //    200,000
    int*    cnt_c = (int*)   (ws + 39800000);    //    400,000
    int*    ptr_r = (int*)   (ws + 40200000);    //    200,004
    int*    ptr_c = (int*)   (ws + 40400004);    //    400,004
    int*    ofs_r = (int*)   (ws + 40800008);    //    200,000
    int*    ofs_c = (int*)   (ws + 41000008);    //    400,000 (+8 pad)
    int2*   srtT  = (int2*)  (ws + 41400016);    //  8,000,000
    int2*   srtS  = (int2*)  (ws + 49400016);    //  8,000,000

    hipMemsetAsync(ws + 39600000, 0, 600000, stream);  // cnt_r + cnt_c

    gemm_msg<<<N_SRC / 4, 256, 0, stream>>>(x_source, w_s, att, 0,  s_msg, es_d);
    gemm_msg<<<N_TGT / 4, 256, 0, stream>>>(x_target, w_t, att, 64, t_msg, et_d);

    hist_kernel<<<(N_EDGES + 255) / 256, 256, 0, stream>>>(rows, cols, cnt_r, cnt_c);
    scan_two<<<2, 1024, 0, stream>>>(cnt_r, cnt_c, ptr_r, ofs_r, ptr_c, ofs_c);
    scatter_kernel<<<(N_EDGES + 255) / 256, 256, 0, stream>>>(
        rows, cols, nbhd, ofs_r, ofs_c, srtT, srtS);

    gather_both<<<(N_TGT + N_SRC + 3) / 4, 256, 0, stream>>>(
        srtT, ptr_r, s_msg, msg_tgt, srtS, ptr_c, t_msg, msg_src, es_d, et_d);
}